// Round 8
// baseline (273.735 us; speedup 1.0000x reference)
//
#include <hip/hip_runtime.h>
#include <hip/hip_bf16.h>
#include <math.h>

// Problem constants
#define B 4
#define N 1024
#define C 768
#define H 8
#define D 96

typedef _Float16 half8 __attribute__((ext_vector_type(8)));
typedef _Float16 half4 __attribute__((ext_vector_type(4)));
typedef float f32x4 __attribute__((ext_vector_type(4)));

#define BN_RSQ 0.9999950000374997f    // 1/sqrt(1+1e-5)
#define QK_SCALE 0.10206207261596577f // 96^-0.5

// ---------------------------------------------------------------------------
// K1: per-token 3x3 conv, SAME padding, (3,16,16) images. f32 in -> f16 out.
// ---------------------------------------------------------------------------
__global__ __launch_bounds__(256) void conv_tok(const float* __restrict__ x,
                                                const float* __restrict__ w,
                                                _Float16* __restrict__ out) {
    __shared__ float sx[768];
    __shared__ float sw[81];
    int t = blockIdx.x;
    const float* xt = x + (size_t)t * 768;
    int tid = threadIdx.x;
    sx[tid]       = xt[tid];
    sx[tid + 256] = xt[tid + 256];
    sx[tid + 512] = xt[tid + 512];
    if (tid < 81) sw[tid] = w[tid];
    __syncthreads();
    int i = tid >> 4, j = tid & 15;
    float acc0 = 0.f, acc1 = 0.f, acc2 = 0.f;
    #pragma unroll
    for (int c = 0; c < 3; ++c) {
        #pragma unroll
        for (int di = 0; di < 3; ++di) {
            int ii = i + di - 1;
            if (ii < 0 || ii > 15) continue;
            #pragma unroll
            for (int dj = 0; dj < 3; ++dj) {
                int jj = j + dj - 1;
                if (jj < 0 || jj > 15) continue;
                float xv = sx[c * 256 + ii * 16 + jj];
                acc0 += xv * sw[(0 * 3 + c) * 9 + di * 3 + dj];
                acc1 += xv * sw[(1 * 3 + c) * 9 + di * 3 + dj];
                acc2 += xv * sw[(2 * 3 + c) * 9 + di * 3 + dj];
            }
        }
    }
    _Float16* ot = out + (size_t)t * 768;
    ot[0 * 256 + tid] = (_Float16)acc0;
    ot[1 * 256 + tid] = (_Float16)acc1;
    ot[2 * 256 + tid] = (_Float16)acc2;
}

// ---------------------------------------------------------------------------
// K2: transpose V: vcT[b*768 + c][m] = vcH[b*N + m][c]   (f16)
// ---------------------------------------------------------------------------
__global__ __launch_bounds__(256) void transpose_v(const _Float16* __restrict__ vcH,
                                                   _Float16* __restrict__ vcT) {
    __shared__ _Float16 tile[64][66];
    int n0 = blockIdx.x * 64, c0 = blockIdx.y * 64, b = blockIdx.z;
    int tid = threadIdx.x;
    for (int i = tid; i < 4096; i += 256) {
        int r = i >> 6, c = i & 63;
        tile[r][c] = vcH[((size_t)(b * N + n0 + r)) * C + c0 + c];
    }
    __syncthreads();
    for (int i = tid; i < 4096; i += 256) {
        int cr = i >> 6, nc = i & 63;
        vcT[((size_t)(b * 768 + c0 + cr)) * N + n0 + nc] = tile[nc][cr];
    }
}

// ---------------------------------------------------------------------------
// K3: vsum[row] = sum_m vcT[row][m], row = b*768+c. One wave per row.
// ---------------------------------------------------------------------------
__global__ __launch_bounds__(256) void vsum_row(const _Float16* __restrict__ vcT,
                                                float* __restrict__ vsum) {
    int row = blockIdx.x * 4 + (threadIdx.x >> 6);
    int lane = threadIdx.x & 63;
    const _Float16* p = vcT + (size_t)row * N;
    float s = 0.f;
    #pragma unroll
    for (int it = 0; it < 2; ++it) {
        half8 v = *(const half8*)(p + (it * 64 + lane) * 8);
        #pragma unroll
        for (int i = 0; i < 8; ++i) s += (float)v[i];
    }
    #pragma unroll
    for (int off = 1; off < 64; off <<= 1) s += __shfl_xor(s, off);
    if (lane == 0) vsum[row] = s;
}

// ---------------------------------------------------------------------------
// K4: Lrow[z*N + n] = sum_m exp(scale * dot(q_n, k_m)).  No S write.
// grid (8 n-tiles of 128, 32 bh), block 256 (4 waves, 2x2).
// Derived from the verified qk_mfma (same staging/fragments), m-loop added.
// ---------------------------------------------------------------------------
__global__ __launch_bounds__(256) void lrow_mfma(const _Float16* __restrict__ qcH,
                                                 const _Float16* __restrict__ kcH,
                                                 float* __restrict__ Lrow) {
    __shared__ __align__(16) char smem[49152];   // Q(24K) | K(24K)
    char* Qb = smem;
    char* Kb = smem + 24576;
    const int n0 = blockIdx.x * 128, z = blockIdx.y;
    const int b = z >> 3, h = z & 7;
    const int tid = threadIdx.x;
    const _Float16* qg = qcH + ((size_t)(b * N + n0)) * C + h * D;
    const _Float16* kgb = kcH + ((size_t)(b * N)) * C + h * D;
    // stage Q once
    #pragma unroll
    for (int it = 0; it < 6; ++it) {
        int chunk = it * 256 + tid;          // 0..1535
        int r = chunk / 12, cc = (chunk - r * 12) * 8;
        half8 qv = *(const half8*)(qg + (size_t)r * C + cc);
        *(half8*)(Qb + (((r * 96 + cc) * 2) ^ ((r & 7) << 4))) = qv;
    }
    const int wid = tid >> 6, lane = tid & 63;
    const int wr = wid >> 1, wc = wid & 1;
    const int l15 = lane & 15, l4 = lane >> 4;
    float rs[4][4] = {};                     // [fm][j] partial row sums
    for (int m0 = 0; m0 < 1024; m0 += 128) {
        __syncthreads();   // prev iter done reading Kb (and Q staged, 1st iter)
        #pragma unroll
        for (int it = 0; it < 6; ++it) {
            int chunk = it * 256 + tid;
            int r = chunk / 12, cc = (chunk - r * 12) * 8;
            half8 kv = *(const half8*)(kgb + (size_t)(m0 + r) * C + cc);
            *(half8*)(Kb + (((r * 96 + cc) * 2) ^ ((r & 7) << 4))) = kv;
        }
        __syncthreads();
        f32x4 acc[4][4] = {};
        #pragma unroll
        for (int ks = 0; ks < 3; ++ks) {
            int k0 = ks * 32 + l4 * 8;
            half8 a[4], bf[4];
            #pragma unroll
            for (int fm = 0; fm < 4; ++fm) {
                int row = wr * 64 + fm * 16 + l15;
                a[fm] = *(half8*)(Qb + (((row * 96 + k0) * 2) ^ ((row & 7) << 4)));
            }
            #pragma unroll
            for (int fn = 0; fn < 4; ++fn) {
                int row = wc * 64 + fn * 16 + l15;
                bf[fn] = *(half8*)(Kb + (((row * 96 + k0) * 2) ^ ((row & 7) << 4)));
            }
            #pragma unroll
            for (int fm = 0; fm < 4; ++fm)
                #pragma unroll
                for (int fn = 0; fn < 4; ++fn)
                    acc[fm][fn] = __builtin_amdgcn_mfma_f32_16x16x32_f16(a[fm], bf[fn], acc[fm][fn], 0, 0, 0);
        }
        #pragma unroll
        for (int fm = 0; fm < 4; ++fm)
            #pragma unroll
            for (int j = 0; j < 4; ++j) {
                float s = 0.f;
                #pragma unroll
                for (int fn = 0; fn < 4; ++fn)
                    s += __expf(acc[fm][fn][j] * QK_SCALE);
                rs[fm][j] += s;
            }
    }
    #pragma unroll
    for (int fm = 0; fm < 4; ++fm)
        #pragma unroll
        for (int j = 0; j < 4; ++j) {
            float s = rs[fm][j];
            s += __shfl_xor(s, 1);
            s += __shfl_xor(s, 2);
            s += __shfl_xor(s, 4);
            s += __shfl_xor(s, 8);
            if (l15 == 0)
                atomicAdd(&Lrow[z * N + n0 + wr * 64 + fm * 16 + l4 * 4 + j], s);
        }
}

// ---------------------------------------------------------------------------
// K5: fused QK^T-recompute + exp + normalize + head-mix + PV.
// grid (32 n-tiles of 32, 2 m-halves, B), block 512 (8 waves; wave = head).
// P/A' in 32 KB LDS [h][32 n][64 m], XOR-swizzled. x via atomicAdd (2 writers).
// ---------------------------------------------------------------------------
__global__ __launch_bounds__(512) void mixpv(const _Float16* __restrict__ qcH,
                                             const _Float16* __restrict__ kcH,
                                             const _Float16* __restrict__ vcT,
                                             const float* __restrict__ Lrow,
                                             const float* __restrict__ rw,
                                             const float* __restrict__ gamma,
                                             float* __restrict__ x) {
    __shared__ __align__(16) _Float16 P[8 * 32 * 64];   // 32 KB
    __shared__ float w2s[64];
    const int n0 = blockIdx.x * 32;
    const int msbase = blockIdx.y * 512;
    const int b = blockIdx.z;
    const int tid = threadIdx.x;
    if (tid < 64) {
        int g = tid >> 3, hh = tid & 7;
        w2s[tid] = gamma[g] * BN_RSQ * rw[g * 8 + hh];
    }
    const int n_t = tid >> 4;            // 0..31 (mix row)
    const int mq4 = (tid & 15) * 4;      // 0..60 (mix m quad)
    float IL[8];
    #pragma unroll
    for (int h = 0; h < 8; ++h)
        IL[h] = 1.0f / Lrow[(size_t)(b * 8 + h) * N + n0 + n_t];
    const int wid = tid >> 6, lane = tid & 63;   // wid = head h = group g
    const int l15 = lane & 15, l4 = lane >> 4;
    char* Pb = (char*)P;
    // Q fragments direct from global (wave-private head, no sharing)
    half8 q8[2][3];
    #pragma unroll
    for (int fm = 0; fm < 2; ++fm)
        #pragma unroll
        for (int ks = 0; ks < 3; ++ks)
            q8[fm][ks] = *(const half8*)(qcH + (size_t)(b * N + n0 + fm * 16 + l15) * C
                                         + wid * 96 + ks * 32 + l4 * 8);
    __syncthreads();   // w2s visible
    f32x4 acc_u[2][6] = {};
    for (int mt = 0; mt < 8; ++mt) {
        const int m0 = msbase + mt * 64;
        // --- QK^T + exp -> P[h] ---
        #pragma unroll
        for (int fn = 0; fn < 4; ++fn) {
            half8 kf[3];
            #pragma unroll
            for (int ks = 0; ks < 3; ++ks)
                kf[ks] = *(const half8*)(kcH + (size_t)(b * N + m0 + fn * 16 + l15) * C
                                         + wid * 96 + ks * 32 + l4 * 8);
            f32x4 a4[2] = {};
            #pragma unroll
            for (int ks = 0; ks < 3; ++ks)
                #pragma unroll
                for (int fm = 0; fm < 2; ++fm)
                    a4[fm] = __builtin_amdgcn_mfma_f32_16x16x32_f16(q8[fm][ks], kf[ks], a4[fm], 0, 0, 0);
            #pragma unroll
            for (int fm = 0; fm < 2; ++fm)
                #pragma unroll
                for (int j = 0; j < 4; ++j) {
                    float p = __expf(a4[fm][j] * QK_SCALE);
                    int n = fm * 16 + l4 * 4 + j;
                    int m = fn * 16 + l15;
                    *(_Float16*)(Pb + wid * 4096 + ((n * 128 + m * 2) ^ ((n & 7) << 4))) = (_Float16)p;
                }
        }
        __syncthreads();   // all heads' P written
        // --- in-place mix: thread owns (n_t, mq4..mq4+3) for all h and g ---
        {
            f32x4 vmix[8] = {};
            #pragma unroll
            for (int h = 0; h < 8; ++h) {
                half4 p4 = *(half4*)(Pb + h * 4096 + ((n_t * 128 + mq4 * 2) ^ ((n_t & 7) << 4)));
                f32x4 pq;
                #pragma unroll
                for (int i = 0; i < 4; ++i) pq[i] = (float)p4[i] * IL[h];
                #pragma unroll
                for (int g = 0; g < 8; ++g) {
                    float wv = w2s[g * 8 + h];
                    #pragma unroll
                    for (int i = 0; i < 4; ++i) vmix[g][i] += wv * pq[i];
                }
            }
            #pragma unroll
            for (int g = 0; g < 8; ++g) {
                half4 hv;
                #pragma unroll
                for (int i = 0; i < 4; ++i) hv[i] = (_Float16)vmix[g][i];
                *(half4*)(Pb + g * 4096 + ((n_t * 128 + mq4 * 2) ^ ((n_t & 7) << 4))) = hv;
            }
        }
        __syncthreads();   // A' ready
        // --- PV: wave = group g = wid; V direct from global (L2) ---
        #pragma unroll
        for (int ks2 = 0; ks2 < 2; ++ks2) {
            half8 af[2];
            #pragma unroll
            for (int fm = 0; fm < 2; ++fm) {
                int n = fm * 16 + l15;
                af[fm] = *(half8*)(Pb + wid * 4096 + ((n * 128 + (ks2 * 32 + l4 * 8) * 2) ^ ((n & 7) << 4)));
            }
            #pragma unroll
            for (int fn2 = 0; fn2 < 6; ++fn2) {
                half8 vf = *(const half8*)(vcT + (size_t)(b * 768 + wid * 96 + fn2 * 16 + l15) * N
                                           + m0 + ks2 * 32 + l4 * 8);
                #pragma unroll
                for (int fm = 0; fm < 2; ++fm)
                    acc_u[fm][fn2] = __builtin_amdgcn_mfma_f32_16x16x32_f16(af[fm], vf, acc_u[fm][fn2], 0, 0, 0);
            }
        }
        __syncthreads();   // PV done before next mt overwrites P
    }
    #pragma unroll
    for (int fm = 0; fm < 2; ++fm)
        #pragma unroll
        for (int fn2 = 0; fn2 < 6; ++fn2)
            #pragma unroll
            for (int j = 0; j < 4; ++j) {
                int n = n0 + fm * 16 + l4 * 4 + j;
                int c = wid * 96 + fn2 * 16 + l15;
                atomicAdd(&x[((size_t)(b * N + n)) * C + c], acc_u[fm][fn2][j]);
            }
}

// ---------------------------------------------------------------------------
// K6: projection out = (x + cg*vsum) @ pw^T + pb  with f16 MFMA.
// grid (32 t-tiles x128, 8 c'-tiles x96). block 256 (4 waves, 2x2).
// ---------------------------------------------------------------------------
__global__ __launch_bounds__(256) void proj_mfma(const float* __restrict__ x,
                                                 const float* __restrict__ vsum,
                                                 const float* __restrict__ pw,
                                                 const float* __restrict__ pb,
                                                 const float* __restrict__ rb,
                                                 const float* __restrict__ gamma,
                                                 const float* __restrict__ beta,
                                                 float* __restrict__ out) {
    __shared__ _Float16 sX[128 * 32];
    __shared__ _Float16 sW[96 * 32];
    const int t0 = blockIdx.x * 128, c0 = blockIdx.y * 96;
    const int b = t0 >> 10;
    const int tid = threadIdx.x;
    const int wid = tid >> 6, lane = tid & 63;
    const int wr = wid >> 1, wc = wid & 1;
    const int l15 = lane & 15, l4 = lane >> 4;
    char* Xb = (char*)sX;
    char* Wb = (char*)sW;
    f32x4 acc[4][3] = {};
    for (int k0 = 0; k0 < 768; k0 += 32) {
        __syncthreads();   // prev MFMA done
        #pragma unroll
        for (int it = 0; it < 4; ++it) {
            int q = it * 256 + tid;            // 0..1023
            int r = q >> 3, c4 = (q & 7) * 4;
            f32x4 xv = *(const f32x4*)(x + (size_t)(t0 + r) * C + k0 + c4);
            int g = (k0 + c4) / 96;
            float cg = gamma[g] * BN_RSQ * rb[g] + beta[g];
            const f32x4 vs = *(const f32x4*)(vsum + b * 768 + k0 + c4);
            half4 hv;
            #pragma unroll
            for (int i = 0; i < 4; ++i) hv[i] = (_Float16)(xv[i] + cg * vs[i]);
            *(half4*)(Xb + (((r * 32 + c4) * 2) ^ ((r & 7) << 4))) = hv;
        }
        #pragma unroll
        for (int it = 0; it < 3; ++it) {
            int q = it * 256 + tid;            // 0..767
            int r = q >> 3, c4 = (q & 7) * 4;
            f32x4 wv = *(const f32x4*)(pw + (size_t)(c0 + r) * C + k0 + c4);
            half4 hv;
            #pragma unroll
            for (int i = 0; i < 4; ++i) hv[i] = (_Float16)wv[i];
            *(half4*)(Wb + (((r * 32 + c4) * 2) ^ ((r & 7) << 4))) = hv;
        }
        __syncthreads();
        half8 af[4];
        #pragma unroll
        for (int fm = 0; fm < 4; ++fm) {
            int r = wr * 64 + fm * 16 + l15;
            af[fm] = *(half8*)(Xb + (((r * 32 + l4 * 8) * 2) ^ ((r & 7) << 4)));
        }
        #pragma unroll
        for (int fn = 0; fn < 3; ++fn) {
            int r = wc * 48 + fn * 16 + l15;
            half8 bf = *(half8*)(Wb + (((r * 32 + l4 * 8) * 2) ^ ((r & 7) << 4)));
            #pragma unroll
            for (int fm = 0; fm < 4; ++fm)
                acc[fm][fn] = __builtin_amdgcn_mfma_f32_16x16x32_f16(af[fm], bf, acc[fm][fn], 0, 0, 0);
        }
    }
    #pragma unroll
    for (int fm = 0; fm < 4; ++fm)
        #pragma unroll
        for (int fn = 0; fn < 3; ++fn) {
            int cc = c0 + wc * 48 + fn * 16 + l15;
            float bias = pb[cc];
            #pragma unroll
            for (int j = 0; j < 4; ++j) {
                int t = t0 + wr * 64 + fm * 16 + l4 * 4 + j;
                out[(size_t)t * C + cc] = acc[fm][fn][j] + bias;
            }
        }
}

// ---------------------------------------------------------------------------
extern "C" void kernel_launch(void* const* d_in, const int* in_sizes, int n_in,
                              void* d_out, int out_size, void* d_ws, size_t ws_size,
                              hipStream_t stream) {
    const float* q     = (const float*)d_in[0];
    const float* k     = (const float*)d_in[1];
    const float* v     = (const float*)d_in[2];
    const float* qw    = (const float*)d_in[3];
    const float* kw    = (const float*)d_in[4];
    const float* vw    = (const float*)d_in[5];
    const float* rw    = (const float*)d_in[6];
    const float* rb    = (const float*)d_in[7];
    const float* gamma = (const float*)d_in[8];
    const float* beta  = (const float*)d_in[9];
    const float* pw    = (const float*)d_in[10];
    const float* pb    = (const float*)d_in[11];
    float* out = (float*)d_out;

    // Workspace layout (bytes, 256-aligned):
    char* ws = (char*)d_ws;
    float*    xacc = (float*)ws;                          // 12,582,912 B
    _Float16* qcH  = (_Float16*)(ws + 12582912);          //  6,291,456 B
    _Float16* kcH  = (_Float16*)(ws + 18874368);
    _Float16* vcH  = (_Float16*)(ws + 25165824);
    _Float16* vcT  = (_Float16*)(ws + 31457280);
    float*    Lrow = (float*)(ws + 37748736);             //    131,072 B
    float*    vsum = (float*)(ws + 37879808);             //     12,288 B
    // total ~38 MB

    hipMemsetAsync(Lrow, 0, 131072, stream);
    hipMemsetAsync(xacc, 0, 12582912, stream);

    conv_tok<<<dim3(B * N), dim3(256), 0, stream>>>(q, qw, qcH);
    conv_tok<<<dim3(B * N), dim3(256), 0, stream>>>(k, kw, kcH);
    conv_tok<<<dim3(B * N), dim3(256), 0, stream>>>(v, vw, vcH);

    transpose_v<<<dim3(16, 12, B), dim3(256), 0, stream>>>(vcH, vcT);
    vsum_row<<<dim3(768), dim3(256), 0, stream>>>(vcT, vsum);

    lrow_mfma<<<dim3(8, 32), dim3(256), 0, stream>>>(qcH, kcH, Lrow);

    mixpv<<<dim3(32, 2, B), dim3(512), 0, stream>>>(qcH, kcH, vcT, Lrow, rw, gamma, xacc);

    proj_mfma<<<dim3(32, 8), dim3(256), 0, stream>>>(xacc, vsum, pw, pb, rb, gamma, beta, out);
}

// Round 11
// 273.062 us; speedup vs baseline: 1.0025x; 1.0025x over previous
//
#include <hip/hip_runtime.h>
#include <hip/hip_bf16.h>
#include <math.h>

// Problem constants
#define B 4
#define N 1024
#define C 768
#define H 8
#define D 96

typedef _Float16 half8 __attribute__((ext_vector_type(8)));
typedef _Float16 half4 __attribute__((ext_vector_type(4)));
typedef _Float16 h2 __attribute__((ext_vector_type(2)));
typedef float f32x4 __attribute__((ext_vector_type(4)));

#define BN_RSQ 0.9999950000374997f    // 1/sqrt(1+1e-5)
#define QK_SCALE 0.10206207261596577f // 96^-0.5

static __device__ __forceinline__ h2 u32_to_h2(unsigned int u) {
    union { unsigned int u; h2 h; } c; c.u = u; return c.h;
}

// ---------------------------------------------------------------------------
// K0: pre-splat w2[g,h] = gamma[g]*BN_RSQ*rw[g,h] into half2 (both lanes eq).
// ---------------------------------------------------------------------------
__global__ __launch_bounds__(64) void w2prep(const float* __restrict__ rw,
                                             const float* __restrict__ gamma,
                                             unsigned int* __restrict__ w2pk) {
    int t = threadIdx.x;            // 0..63
    int g = t >> 3, h = t & 7;
    float w = gamma[g] * BN_RSQ * rw[g * 8 + h];
    union { _Float16 f; unsigned short s; } c; c.f = (_Float16)w;
    w2pk[t] = (unsigned int)c.s | ((unsigned int)c.s << 16);
}

// ---------------------------------------------------------------------------
// K1: per-token 3x3 conv for q/k/v in one launch (blockIdx.y selects tensor).
// ---------------------------------------------------------------------------
__global__ __launch_bounds__(256) void conv_all(const float* __restrict__ q,
                                                const float* __restrict__ k,
                                                const float* __restrict__ v,
                                                const float* __restrict__ qw,
                                                const float* __restrict__ kw,
                                                const float* __restrict__ vw,
                                                _Float16* __restrict__ qo,
                                                _Float16* __restrict__ ko,
                                                _Float16* __restrict__ vo) {
    const int sel = blockIdx.y;
    const float* x = sel == 0 ? q : sel == 1 ? k : v;
    const float* w = sel == 0 ? qw : sel == 1 ? kw : vw;
    _Float16* out = sel == 0 ? qo : sel == 1 ? ko : vo;
    __shared__ float sx[768];
    __shared__ float sw[81];
    int t = blockIdx.x;
    const float* xt = x + (size_t)t * 768;
    int tid = threadIdx.x;
    sx[tid]       = xt[tid];
    sx[tid + 256] = xt[tid + 256];
    sx[tid + 512] = xt[tid + 512];
    if (tid < 81) sw[tid] = w[tid];
    __syncthreads();
    int i = tid >> 4, j = tid & 15;
    float acc0 = 0.f, acc1 = 0.f, acc2 = 0.f;
    #pragma unroll
    for (int c = 0; c < 3; ++c) {
        #pragma unroll
        for (int di = 0; di < 3; ++di) {
            int ii = i + di - 1;
            if (ii < 0 || ii > 15) continue;
            #pragma unroll
            for (int dj = 0; dj < 3; ++dj) {
                int jj = j + dj - 1;
                if (jj < 0 || jj > 15) continue;
                float xv = sx[c * 256 + ii * 16 + jj];
                acc0 += xv * sw[(0 * 3 + c) * 9 + di * 3 + dj];
                acc1 += xv * sw[(1 * 3 + c) * 9 + di * 3 + dj];
                acc2 += xv * sw[(2 * 3 + c) * 9 + di * 3 + dj];
            }
        }
    }
    _Float16* ot = out + (size_t)t * 768;
    ot[0 * 256 + tid] = (_Float16)acc0;
    ot[1 * 256 + tid] = (_Float16)acc1;
    ot[2 * 256 + tid] = (_Float16)acc2;
}

// ---------------------------------------------------------------------------
// K2: transpose V: vcT[b*768 + c][m] = vcH[b*N + m][c]   (f16)
// ---------------------------------------------------------------------------
__global__ __launch_bounds__(256) void transpose_v(const _Float16* __restrict__ vcH,
                                                   _Float16* __restrict__ vcT) {
    __shared__ _Float16 tile[64][66];
    int n0 = blockIdx.x * 64, c0 = blockIdx.y * 64, b = blockIdx.z;
    int tid = threadIdx.x;
    for (int i = tid; i < 4096; i += 256) {
        int r = i >> 6, c = i & 63;
        tile[r][c] = vcH[((size_t)(b * N + n0 + r)) * C + c0 + c];
    }
    __syncthreads();
    for (int i = tid; i < 4096; i += 256) {
        int cr = i >> 6, nc = i & 63;
        vcT[((size_t)(b * 768 + c0 + cr)) * N + n0 + nc] = tile[nc][cr];
    }
}

// ---------------------------------------------------------------------------
// K3: vsum[row] = sum_m vcT[row][m], row = b*768+c. One wave per row.
// ---------------------------------------------------------------------------
__global__ __launch_bounds__(256) void vsum_row(const _Float16* __restrict__ vcT,
                                                float* __restrict__ vsum) {
    int row = blockIdx.x * 4 + (threadIdx.x >> 6);
    int lane = threadIdx.x & 63;
    const _Float16* p = vcT + (size_t)row * N;
    float s = 0.f;
    #pragma unroll
    for (int it = 0; it < 2; ++it) {
        half8 v = *(const half8*)(p + (it * 64 + lane) * 8);
        #pragma unroll
        for (int i = 0; i < 8; ++i) s += (float)v[i];
    }
    #pragma unroll
    for (int off = 1; off < 64; off <<= 1) s += __shfl_xor(s, off);
    if (lane == 0) vsum[row] = s;
}

// ---------------------------------------------------------------------------
// K4: Lrow[z*N + n] = sum_m exp(scale * dot(q_n, k_m)).  No S write.
// 1-D grid 512, XCD-grouped decode: z low bits pin (b,h) to one XCD so K is
// L2-resident. Each block: 128-row n-tile, one m-half (512), atomicAdd Lrow.
// ---------------------------------------------------------------------------
__global__ __launch_bounds__(256) void lrow_mfma(const _Float16* __restrict__ qcH,
                                                 const _Float16* __restrict__ kcH,
                                                 float* __restrict__ Lrow) {
    __shared__ __align__(16) char smem[49152];   // Q(24K) | K(24K)
    char* Qb = smem;
    char* Kb = smem + 24576;
    const int id = blockIdx.x;                       // 0..511
    const int z = (id & 7) | (((id >> 3) & 3) << 3); // bh 0..31; XCD = z&7
    const int r4 = id >> 5;                          // 0..15
    const int n0 = (r4 & 7) * 128;
    const int mh = r4 >> 3;                          // m-half
    const int b = z >> 3, h = z & 7;
    const int tid = threadIdx.x;
    const _Float16* qg = qcH + ((size_t)(b * N + n0)) * C + h * D;
    const _Float16* kgb = kcH + ((size_t)(b * N)) * C + h * D;
    // stage Q once
    #pragma unroll
    for (int it = 0; it < 6; ++it) {
        int chunk = it * 256 + tid;          // 0..1535
        int r = chunk / 12, cc = (chunk - r * 12) * 8;
        half8 qv = *(const half8*)(qg + (size_t)r * C + cc);
        *(half8*)(Qb + (((r * 96 + cc) * 2) ^ ((r & 7) << 4))) = qv;
    }
    const int wid = tid >> 6, lane = tid & 63;
    const int wr = wid >> 1, wc = wid & 1;
    const int l15 = lane & 15, l4 = lane >> 4;
    float rs[4][4] = {};                     // [fm][j] partial row sums
    for (int m0 = mh * 512; m0 < mh * 512 + 512; m0 += 128) {
        __syncthreads();   // prev iter done reading Kb (and Q staged, 1st iter)
        #pragma unroll
        for (int it = 0; it < 6; ++it) {
            int chunk = it * 256 + tid;
            int r = chunk / 12, cc = (chunk - r * 12) * 8;
            half8 kv = *(const half8*)(kgb + (size_t)(m0 + r) * C + cc);
            *(half8*)(Kb + (((r * 96 + cc) * 2) ^ ((r & 7) << 4))) = kv;
        }
        __syncthreads();
        f32x4 acc[4][4] = {};
        #pragma unroll
        for (int ks = 0; ks < 3; ++ks) {
            int k0 = ks * 32 + l4 * 8;
            half8 a[4], bf[4];
            #pragma unroll
            for (int fm = 0; fm < 4; ++fm) {
                int row = wr * 64 + fm * 16 + l15;
                a[fm] = *(half8*)(Qb + (((row * 96 + k0) * 2) ^ ((row & 7) << 4)));
            }
            #pragma unroll
            for (int fn = 0; fn < 4; ++fn) {
                int row = wc * 64 + fn * 16 + l15;
                bf[fn] = *(half8*)(Kb + (((row * 96 + k0) * 2) ^ ((row & 7) << 4)));
            }
            #pragma unroll
            for (int fm = 0; fm < 4; ++fm)
                #pragma unroll
                for (int fn = 0; fn < 4; ++fn)
                    acc[fm][fn] = __builtin_amdgcn_mfma_f32_16x16x32_f16(a[fm], bf[fn], acc[fm][fn], 0, 0, 0);
        }
        #pragma unroll
        for (int fm = 0; fm < 4; ++fm)
            #pragma unroll
            for (int j = 0; j < 4; ++j) {
                float s = 0.f;
                #pragma unroll
                for (int fn = 0; fn < 4; ++fn)
                    s += __expf(acc[fm][fn][j] * QK_SCALE);
                rs[fm][j] += s;
            }
    }
    #pragma unroll
    for (int fm = 0; fm < 4; ++fm)
        #pragma unroll
        for (int j = 0; j < 4; ++j) {
            float s = rs[fm][j];
            s += __shfl_xor(s, 1);
            s += __shfl_xor(s, 2);
            s += __shfl_xor(s, 4);
            s += __shfl_xor(s, 8);
            if (l15 == 0)
                atomicAdd(&Lrow[z * N + n0 + wr * 64 + fm * 16 + l4 * 4 + j], s);
        }
}

// ---------------------------------------------------------------------------
// K5: fused QK^T-recompute + exp + normalize + head-mix (packed f16, SGPR
// weights) + PV. 1-D grid 512, XCD-grouped: (b,quarter) pinned per XCD so
// K/V slices are L2-resident. block 512 (8 waves; wave = head).
// P/A' in 32 KB LDS [h][32 n][64 m], XOR-swizzled. x via atomicAdd (4 writers).
// ---------------------------------------------------------------------------
__global__ __launch_bounds__(512) void mixpv(const _Float16* __restrict__ qcH,
                                             const _Float16* __restrict__ kcH,
                                             const _Float16* __restrict__ vcT,
                                             const float* __restrict__ Lrow,
                                             const unsigned int* __restrict__ w2pk,
                                             float* __restrict__ x) {
    __shared__ __align__(16) _Float16 P[8 * 32 * 64];   // 32 KB
    const int gid = blockIdx.x;          // 0..511
    const int grp = gid & 15;            // XCD = gid&7; (b,qtr) pairs per XCD
    const int b = grp >> 2, qtr = grp & 3;
    const int n0 = (gid >> 4) * 32;
    const int msbase = qtr * 256;
    const int tid = threadIdx.x;
    const int n_t = tid >> 4;            // 0..31 (mix row)
    const int mq4 = (tid & 15) * 4;      // 0..60 (mix m quad)
    // per-thread 1/L as splatted half2
    h2 IL2[8];
    #pragma unroll
    for (int h = 0; h < 8; ++h) {
        float il = 1.0f / Lrow[(size_t)(b * 8 + h) * N + n0 + n_t];
        _Float16 i16 = (_Float16)il;
        h2 t; t[0] = i16; t[1] = i16;
        IL2[h] = t;
    }
    const int wid = tid >> 6, lane = tid & 63;   // wid = head h = group g
    const int l15 = lane & 15, l4 = lane >> 4;
    char* Pb = (char*)P;
    // Q fragments direct from global (wave-private head)
    half8 q8[2][3];
    #pragma unroll
    for (int fm = 0; fm < 2; ++fm)
        #pragma unroll
        for (int ks = 0; ks < 3; ++ks)
            q8[fm][ks] = *(const half8*)(qcH + (size_t)(b * N + n0 + fm * 16 + l15) * C
                                         + wid * 96 + ks * 32 + l4 * 8);
    f32x4 acc_u[2][6] = {};
    for (int mt = 0; mt < 4; ++mt) {
        const int m0 = msbase + mt * 64;
        // --- QK^T + exp -> P[h] ---
        #pragma unroll
        for (int fn = 0; fn < 4; ++fn) {
            half8 kf[3];
            #pragma unroll
            for (int ks = 0; ks < 3; ++ks)
                kf[ks] = *(const half8*)(kcH + (size_t)(b * N + m0 + fn * 16 + l15) * C
                                         + wid * 96 + ks * 32 + l4 * 8);
            f32x4 a4[2] = {};
            #pragma unroll
            for (int ks = 0; ks < 3; ++ks)
                #pragma unroll
                for (int fm = 0; fm < 2; ++fm)
                    a4[fm] = __builtin_amdgcn_mfma_f32_16x16x32_f16(q8[fm][ks], kf[ks], a4[fm], 0, 0, 0);
            #pragma unroll
            for (int fm = 0; fm < 2; ++fm)
                #pragma unroll
                for (int j = 0; j < 4; ++j) {
                    float p = __expf(a4[fm][j] * QK_SCALE);
                    int n = fm * 16 + l4 * 4 + j;
                    int m = fn * 16 + l15;
                    *(_Float16*)(Pb + wid * 4096 + ((n * 128 + m * 2) ^ ((n & 7) << 4))) = (_Float16)p;
                }
        }
        __syncthreads();   // all heads' P written
        // --- in-place mix (packed f16): thread owns (n_t, mq4..+3) for all h,g
        {
            h2 pn0[8], pn1[8];
            #pragma unroll
            for (int h = 0; h < 8; ++h) {
                half4 p4 = *(half4*)(Pb + h * 4096 + ((n_t * 128 + mq4 * 2) ^ ((n_t & 7) << 4)));
                h2 lo; lo[0] = p4[0]; lo[1] = p4[1];
                h2 hi; hi[0] = p4[2]; hi[1] = p4[3];
                pn0[h] = lo * IL2[h];
                pn1[h] = hi * IL2[h];
            }
            #pragma unroll
            for (int g = 0; g < 8; ++g) {
                h2 a0 = {(_Float16)0.f, (_Float16)0.f};
                h2 a1 = a0;
                #pragma unroll
                for (int h = 0; h < 8; ++h) {
                    h2 w = u32_to_h2(w2pk[g * 8 + h]);   // uniform -> SGPR
                    a0 = w * pn0[h] + a0;
                    a1 = w * pn1[h] + a1;
                }
                half4 o; o[0] = a0[0]; o[1] = a0[1]; o[2] = a1[0]; o[3] = a1[1];
                *(half4*)(Pb + g * 4096 + ((n_t * 128 + mq4 * 2) ^ ((n_t & 7) << 4))) = o;
            }
        }
        __syncthreads();   // A' ready
        // --- PV: wave = group g = wid; V direct from global (L2) ---
        #pragma unroll
        for (int ks2 = 0; ks2 < 2; ++ks2) {
            half8 af[2];
            #pragma unroll
            for (int fm = 0; fm < 2; ++fm) {
                int n = fm * 16 + l15;
                af[fm] = *(half8*)(Pb + wid * 4096 + ((n * 128 + (ks2 * 32 + l4 * 8) * 2) ^ ((n & 7) << 4)));
            }
            #pragma unroll
            for (int fn2 = 0; fn2 < 6; ++fn2) {
                half8 vf = *(const half8*)(vcT + (size_t)(b * 768 + wid * 96 + fn2 * 16 + l15) * N
                                           + m0 + ks2 * 32 + l4 * 8);
                #pragma unroll
                for (int fm = 0; fm < 2; ++fm)
                    acc_u[fm][fn2] = __builtin_amdgcn_mfma_f32_16x16x32_f16(af[fm], vf, acc_u[fm][fn2], 0, 0, 0);
            }
        }
        __syncthreads();   // PV done before next mt overwrites P
    }
    #pragma unroll
    for (int fm = 0; fm < 2; ++fm)
        #pragma unroll
        for (int fn2 = 0; fn2 < 6; ++fn2)
            #pragma unroll
            for (int j = 0; j < 4; ++j) {
                int n = n0 + fm * 16 + l4 * 4 + j;
                int c = wid * 96 + fn2 * 16 + l15;
                atomicAdd(&x[((size_t)(b * N + n)) * C + c], acc_u[fm][fn2][j]);
            }
}

// ---------------------------------------------------------------------------
// K6: projection out = (x + cg*vsum) @ pw^T + pb  with f16 MFMA.
// grid (32 t-tiles x128, 8 c'-tiles x96). block 256 (4 waves, 2x2).
// ---------------------------------------------------------------------------
__global__ __launch_bounds__(256) void proj_mfma(const float* __restrict__ x,
                                                 const float* __restrict__ vsum,
                                                 const float* __restrict__ pw,
                                                 const float* __restrict__ pb,
                                                 const float* __restrict__ rb,
                                                 const float* __restrict__ gamma,
                                                 const float* __restrict__ beta,
                                                 float* __restrict__ out) {
    __shared__ _Float16 sX[128 * 32];
    __shared__ _Float16 sW[96 * 32];
    const int t0 = blockIdx.x * 128, c0 = blockIdx.y * 96;
    const int b = t0 >> 10;
    const int tid = threadIdx.x;
    const int wid = tid >> 6, lane = tid & 63;
    const int wr = wid >> 1, wc = wid & 1;
    const int l15 = lane & 15, l4 = lane >> 4;
    char* Xb = (char*)sX;
    char* Wb = (char*)sW;
    f32x4 acc[4][3] = {};
    for (int k0 = 0; k0 < 768; k0 += 32) {
        __syncthreads();   // prev MFMA done
        #pragma unroll
        for (int it = 0; it < 4; ++it) {
            int q = it * 256 + tid;            // 0..1023
            int r = q >> 3, c4 = (q & 7) * 4;
            f32x4 xv = *(const f32x4*)(x + (size_t)(t0 + r) * C + k0 + c4);
            int g = (k0 + c4) / 96;
            float cg = gamma[g] * BN_RSQ * rb[g] + beta[g];
            const f32x4 vs = *(const f32x4*)(vsum + b * 768 + k0 + c4);
            half4 hv;
            #pragma unroll
            for (int i = 0; i < 4; ++i) hv[i] = (_Float16)(xv[i] + cg * vs[i]);
            *(half4*)(Xb + (((r * 32 + c4) * 2) ^ ((r & 7) << 4))) = hv;
        }
        #pragma unroll
        for (int it = 0; it < 3; ++it) {
            int q = it * 256 + tid;            // 0..767
            int r = q >> 3, c4 = (q & 7) * 4;
            f32x4 wv = *(const f32x4*)(pw + (size_t)(c0 + r) * C + k0 + c4);
            half4 hv;
            #pragma unroll
            for (int i = 0; i < 4; ++i) hv[i] = (_Float16)wv[i];
            *(half4*)(Wb + (((r * 32 + c4) * 2) ^ ((r & 7) << 4))) = hv;
        }
        __syncthreads();
        half8 af[4];
        #pragma unroll
        for (int fm = 0; fm < 4; ++fm) {
            int r = wr * 64 + fm * 16 + l15;
            af[fm] = *(half8*)(Xb + (((r * 32 + l4 * 8) * 2) ^ ((r & 7) << 4)));
        }
        #pragma unroll
        for (int fn = 0; fn < 3; ++fn) {
            int r = wc * 48 + fn * 16 + l15;
            half8 bf = *(half8*)(Wb + (((r * 32 + l4 * 8) * 2) ^ ((r & 7) << 4)));
            #pragma unroll
            for (int fm = 0; fm < 4; ++fm)
                acc[fm][fn] = __builtin_amdgcn_mfma_f32_16x16x32_f16(af[fm], bf, acc[fm][fn], 0, 0, 0);
        }
    }
    #pragma unroll
    for (int fm = 0; fm < 4; ++fm)
        #pragma unroll
        for (int fn = 0; fn < 3; ++fn) {
            int cc = c0 + wc * 48 + fn * 16 + l15;
            float bias = pb[cc];
            #pragma unroll
            for (int j = 0; j < 4; ++j) {
                int t = t0 + wr * 64 + fm * 16 + l4 * 4 + j;
                out[(size_t)t * C + cc] = acc[fm][fn][j] + bias;
            }
        }
}

// ---------------------------------------------------------------------------
extern "C" void kernel_launch(void* const* d_in, const int* in_sizes, int n_in,
                              void* d_out, int out_size, void* d_ws, size_t ws_size,
                              hipStream_t stream) {
    const float* q     = (const float*)d_in[0];
    const float* k     = (const float*)d_in[1];
    const float* v     = (const float*)d_in[2];
    const float* qw    = (const float*)d_in[3];
    const float* kw    = (const float*)d_in[4];
    const float* vw    = (const float*)d_in[5];
    const float* rw    = (const float*)d_in[6];
    const float* rb    = (const float*)d_in[7];
    const float* gamma = (const float*)d_in[8];
    const float* beta  = (const float*)d_in[9];
    const float* pw    = (const float*)d_in[10];
    const float* pb    = (const float*)d_in[11];
    float* out = (float*)d_out;

    // Workspace layout (bytes, 256-aligned):
    char* ws = (char*)d_ws;
    float*    xacc = (float*)ws;                          // 12,582,912 B
    _Float16* qcH  = (_Float16*)(ws + 12582912);          //  6,291,456 B
    _Float16* kcH  = (_Float16*)(ws + 18874368);
    _Float16* vcH  = (_Float16*)(ws + 25165824);
    _Float16* vcT  = (_Float16*)(ws + 31457280);
    float*    Lrow = (float*)(ws + 37748736);             //    131,072 B
    float*    vsum = (float*)(ws + 37879808);             //     12,288 B
    unsigned int* w2pk = (unsigned int*)(ws + 37892096);  //        256 B
    // total ~38 MB

    hipMemsetAsync(Lrow, 0, 131072, stream);
    hipMemsetAsync(xacc, 0, 12582912, stream);

    w2prep<<<dim3(1), dim3(64), 0, stream>>>(rw, gamma, w2pk);

    conv_all<<<dim3(B * N, 3), dim3(256), 0, stream>>>(q, k, v, qw, kw, vw, qcH, kcH, vcH);

    transpose_v<<<dim3(16, 12, B), dim3(256), 0, stream>>>(vcH, vcT);
    vsum_row<<<dim3(768), dim3(256), 0, stream>>>(vcT, vsum);

    lrow_mfma<<<dim3(512), dim3(256), 0, stream>>>(qcH, kcH, Lrow);

    mixpv<<<dim3(512), dim3(512), 0, stream>>>(qcH, kcH, vcT, Lrow, w2pk, xacc);

    proj_mfma<<<dim3(32, 8), dim3(256), 0, stream>>>(xacc, vsum, pw, pb, rb, gamma, beta, out);
}